// Round 2
// baseline (1011.441 us; speedup 1.0000x reference)
//
#include <hip/hip_runtime.h>
#include <hip/hip_bf16.h>
#include <math.h>

typedef __hip_bfloat16 bf16;
typedef __attribute__((ext_vector_type(8))) short short8;
typedef __attribute__((ext_vector_type(4))) float f32x4;

#define C_DIM 384
#define SS 3
#define SCALE_ATTN 0.17677669529663687f  // 32^-0.5
#define LN_EPS 1e-5f

// ---------------------------------------------------------------------------
// Weight transpose + fp32->bf16 cast: in fp32 [R][Cc] -> out bf16 [Cc][R]
// ---------------------------------------------------------------------------
__global__ void transpose_cast_kernel(const float* __restrict__ in, bf16* __restrict__ out,
                                      int R, int Cc) {
    int idx = blockIdx.x * 256 + threadIdx.x;
    if (idx < R * Cc) {
        int r = idx / Cc, c = idx - r * Cc;
        out[(size_t)c * R + r] = __float2bfloat16(in[idx]);
    }
}

// ---------------------------------------------------------------------------
// LN1 + cyclic shift + window partition.  One wave per output token.
// token = bw*49 + n ; bw = b*64 + wh*8 + ww ; n = rr*7 + cc
// source position = ((wh*7+rr+SS)%56, (ww*7+cc+SS)%56)
// ---------------------------------------------------------------------------
__global__ __launch_bounds__(256)
void ln1_shift_window(const float* __restrict__ x, const float* __restrict__ g,
                      const float* __restrict__ bta, bf16* __restrict__ win) {
    int wave = threadIdx.x >> 6, lane = threadIdx.x & 63;
    int token = blockIdx.x * 4 + wave;
    int bw = token / 49, ntk = token - bw * 49;
    int bb = bw >> 6, wi = bw & 63;
    int wh = wi >> 3, wwi = wi & 7;
    int rr = ntk / 7, cc = ntk - rr * 7;
    int hs = wh * 7 + rr + SS; if (hs >= 56) hs -= 56;
    int ws = wwi * 7 + cc + SS; if (ws >= 56) ws -= 56;
    const float* src = x + ((size_t)(bb * 3136 + hs * 56 + ws)) * C_DIM;

    float v[6]; float s = 0.f, sq = 0.f;
    #pragma unroll
    for (int j = 0; j < 6; j++) {
        v[j] = src[lane + j * 64];
        s += v[j]; sq += v[j] * v[j];
    }
    #pragma unroll
    for (int o = 32; o > 0; o >>= 1) { s += __shfl_xor(s, o, 64); sq += __shfl_xor(sq, o, 64); }
    float mean = s * (1.0f / 384.0f);
    float var  = sq * (1.0f / 384.0f) - mean * mean;
    float rstd = rsqrtf(var + LN_EPS);

    bf16* dst = win + (size_t)token * C_DIM;
    #pragma unroll
    for (int j = 0; j < 6; j++) {
        int c = lane + j * 64;
        dst[c] = __float2bfloat16((v[j] - mean) * rstd * g[c] + bta[c]);
    }
}

// ---------------------------------------------------------------------------
// LN2 over fp32 xmid -> bf16
// ---------------------------------------------------------------------------
__global__ __launch_bounds__(256)
void ln2_kernel(const float* __restrict__ xmid, const float* __restrict__ g,
                const float* __restrict__ bta, bf16* __restrict__ out) {
    int wave = threadIdx.x >> 6, lane = threadIdx.x & 63;
    int token = blockIdx.x * 4 + wave;
    const float* src = xmid + (size_t)token * C_DIM;
    float v[6]; float s = 0.f, sq = 0.f;
    #pragma unroll
    for (int j = 0; j < 6; j++) {
        v[j] = src[lane + j * 64];
        s += v[j]; sq += v[j] * v[j];
    }
    #pragma unroll
    for (int o = 32; o > 0; o >>= 1) { s += __shfl_xor(s, o, 64); sq += __shfl_xor(sq, o, 64); }
    float mean = s * (1.0f / 384.0f);
    float var  = sq * (1.0f / 384.0f) - mean * mean;
    float rstd = rsqrtf(var + LN_EPS);
    bf16* dst = out + (size_t)token * C_DIM;
    #pragma unroll
    for (int j = 0; j < 6; j++) {
        int c = lane + j * 64;
        dst[c] = __float2bfloat16((v[j] - mean) * rstd * g[c] + bta[c]);
    }
}

// ---------------------------------------------------------------------------
// MFMA bf16 GEMM:  C[M,N] = A[M,K] @ W[K,N] (+ epilogue), W given transposed (N,K) bf16.
// BM=128, BN=64, BK=32, 256 threads (4 waves), each wave 32x64 via 2x4 MFMA 16x16x32.
// LDS panel layout [BK/8][rows][8] -> conflict-free ds_read_b128 for fragments.
// MODE 0: +bias -> bf16 out
// MODE 1: +bias, exact GELU -> bf16 out
// MODE 2: +bias, window-reverse + unshift scatter, + residual x (fp32) -> fp32 out
// MODE 3: +bias, + residual fp32 -> fp32 out (d_out)
// ---------------------------------------------------------------------------
template <int MODE>
__global__ __launch_bounds__(256)
void gemm_kernel(const bf16* __restrict__ A, const bf16* __restrict__ BT,
                 const float* __restrict__ bias, void* __restrict__ out,
                 const float* __restrict__ resid, int M, int N, int K) {
    const int BM = 128, BN = 64, BK = 32;
    __shared__ bf16 As[4][BM][8];
    __shared__ bf16 Bs[4][BN][8];

    int tid = threadIdx.x;
    int wave = tid >> 6, lane = tid & 63, quad = lane >> 4, r = lane & 15;
    int m0 = blockIdx.x * BM, n0 = blockIdx.y * BN;

    f32x4 acc[2][4] = {};

    for (int k0 = 0; k0 < K; k0 += BK) {
        // stage A tile: 128x32 bf16 = 512 x 16B chunks
        #pragma unroll
        for (int i = tid; i < BM * BK / 8; i += 256) {
            int row = i >> 2, panel = i & 3;
            *(uint4*)(&As[panel][row][0]) =
                *(const uint4*)(&A[(size_t)(m0 + row) * K + k0 + panel * 8]);
        }
        // stage B tile: 64x32 bf16 = 256 x 16B chunks
        {
            int n = tid >> 2, panel = tid & 3;
            *(uint4*)(&Bs[panel][n][0]) =
                *(const uint4*)(&BT[(size_t)(n0 + n) * K + k0 + panel * 8]);
        }
        __syncthreads();

        short8 a[2], b[4];
        #pragma unroll
        for (int mt = 0; mt < 2; mt++)
            a[mt] = *(const short8*)(&As[quad][wave * 32 + mt * 16 + r][0]);
        #pragma unroll
        for (int nt = 0; nt < 4; nt++)
            b[nt] = *(const short8*)(&Bs[quad][nt * 16 + r][0]);
        #pragma unroll
        for (int mt = 0; mt < 2; mt++)
            #pragma unroll
            for (int nt = 0; nt < 4; nt++)
                acc[mt][nt] = __builtin_amdgcn_mfma_f32_16x16x32_bf16(
                    a[mt], b[nt], acc[mt][nt], 0, 0, 0);
        __syncthreads();
    }

    // epilogue: acc[mt][nt][reg] -> m = m0+wave*32+mt*16+quad*4+reg, n = n0+nt*16+r
    #pragma unroll
    for (int mt = 0; mt < 2; mt++) {
        #pragma unroll
        for (int nt = 0; nt < 4; nt++) {
            int n = n0 + nt * 16 + r;
            float bv = bias[n];
            #pragma unroll
            for (int reg = 0; reg < 4; reg++) {
                int m = m0 + wave * 32 + mt * 16 + quad * 4 + reg;
                float v = acc[mt][nt][reg] + bv;
                if (MODE == 0) {
                    ((bf16*)out)[(size_t)m * N + n] = __float2bfloat16(v);
                } else if (MODE == 1) {
                    float gl = 0.5f * v * (1.0f + erff(v * 0.70710678118654752f));
                    ((bf16*)out)[(size_t)m * N + n] = __float2bfloat16(gl);
                } else if (MODE == 2) {
                    int bw = m / 49, ntk = m - bw * 49;
                    int bb = bw >> 6, wi = bw & 63;
                    int wh = wi >> 3, wwi = wi & 7;
                    int rr = ntk / 7, cc = ntk - rr * 7;
                    int ho = wh * 7 + rr + SS; if (ho >= 56) ho -= 56;
                    int wo = wwi * 7 + cc + SS; if (wo >= 56) wo -= 56;
                    size_t dst = ((size_t)(bb * 3136 + ho * 56 + wo)) * C_DIM + n;
                    ((float*)out)[dst] = v + resid[dst];
                } else {
                    size_t idx = (size_t)m * N + n;
                    ((float*)out)[idx] = v + resid[idx];
                }
            }
        }
    }
}

// ---------------------------------------------------------------------------
// Windowed attention: one block per (window, head).  qkv bf16: [1024*49, 1152]
// out bf16: [1024*49, 384] with heads re-interleaved.
// ---------------------------------------------------------------------------
__global__ __launch_bounds__(256)
void attn_kernel(const bf16* __restrict__ qkv, const float* __restrict__ rpb,
                 const int* __restrict__ rel_idx, const float* __restrict__ mask,
                 bf16* __restrict__ out) {
    __shared__ float qs[49][32], ks[49][32], vs[49][32];
    __shared__ float S[49][49];
    int bw = blockIdx.x, h = blockIdx.y;
    int tid = threadIdx.x;

    size_t base = (size_t)bw * 49 * 1152 + h * 32;
    for (int i = tid; i < 49 * 32; i += 256) {
        int n = i >> 5, d = i & 31;
        size_t rowoff = base + (size_t)n * 1152 + d;
        qs[n][d] = __bfloat162float(qkv[rowoff]) * SCALE_ATTN;
        ks[n][d] = __bfloat162float(qkv[rowoff + 384]);
        vs[n][d] = __bfloat162float(qkv[rowoff + 768]);
    }
    __syncthreads();

    int wi = bw & 63;
    for (int idx = tid; idx < 49 * 49; idx += 256) {
        int i = idx / 49, j = idx - i * 49;
        float acc = 0.f;
        #pragma unroll
        for (int d = 0; d < 32; d++) acc += qs[i][d] * ks[j][d];
        acc += rpb[rel_idx[idx] * 12 + h];
        acc += mask[(size_t)wi * 2401 + idx];
        S[i][j] = acc;
    }
    __syncthreads();

    if (tid < 49) {
        float m = -1e30f;
        for (int j = 0; j < 49; j++) m = fmaxf(m, S[tid][j]);
        float sum = 0.f;
        for (int j = 0; j < 49; j++) { float e = expf(S[tid][j] - m); S[tid][j] = e; sum += e; }
        float inv = 1.0f / sum;
        for (int j = 0; j < 49; j++) S[tid][j] *= inv;
    }
    __syncthreads();

    for (int i2 = tid; i2 < 49 * 32; i2 += 256) {
        int i = i2 >> 5, d = i2 & 31;
        float acc = 0.f;
        #pragma unroll
        for (int j = 0; j < 49; j++) acc += S[i][j] * vs[j][d];
        out[((size_t)bw * 49 + i) * 384 + h * 32 + d] = __float2bfloat16(acc);
    }
}

// ---------------------------------------------------------------------------
extern "C" void kernel_launch(void* const* d_in, const int* in_sizes, int n_in,
                              void* d_out, int out_size, void* d_ws, size_t ws_size,
                              hipStream_t stream) {
    const float* x      = (const float*)d_in[0];
    const float* g1     = (const float*)d_in[1];
    const float* b1     = (const float*)d_in[2];
    const float* qkv_w  = (const float*)d_in[3];
    const float* qkv_b  = (const float*)d_in[4];
    const float* rpb    = (const float*)d_in[5];
    const float* proj_w = (const float*)d_in[6];
    const float* proj_b = (const float*)d_in[7];
    const float* g2     = (const float*)d_in[8];
    const float* b2     = (const float*)d_in[9];
    const float* fc1_w  = (const float*)d_in[10];
    const float* fc1_b  = (const float*)d_in[11];
    const float* fc2_w  = (const float*)d_in[12];
    const float* fc2_b  = (const float*)d_in[13];
    const int*   rel_idx   = (const int*)d_in[14];
    const float* attn_mask = (const float*)d_in[15];

    const int M = 50176;  // 16 * 56 * 56 tokens = 1024 windows * 49

    char* ws = (char*)d_ws;
    size_t off = 0;
    bf16* bufA   = (bf16*)(ws + off); off += (size_t)M * 384 * 2;    // win / attn_out / ln2out
    bf16* bufBC  = (bf16*)(ws + off); off += (size_t)M * 1536 * 2;   // qkv (1152 cols) then h1 (1536)
    float* xmid  = (float*)(ws + off); off += (size_t)M * 384 * 4;   // residual mid, fp32
    bf16* qkv_wT  = (bf16*)(ws + off); off += (size_t)1152 * 384 * 2;
    bf16* proj_wT = (bf16*)(ws + off); off += (size_t)384 * 384 * 2;
    bf16* fc1_wT  = (bf16*)(ws + off); off += (size_t)1536 * 384 * 2;
    bf16* fc2_wT  = (bf16*)(ws + off); off += (size_t)384 * 1536 * 2;

    transpose_cast_kernel<<<(384 * 1152 + 255) / 256, 256, 0, stream>>>(qkv_w, qkv_wT, 384, 1152);
    transpose_cast_kernel<<<(384 * 384 + 255) / 256, 256, 0, stream>>>(proj_w, proj_wT, 384, 384);
    transpose_cast_kernel<<<(384 * 1536 + 255) / 256, 256, 0, stream>>>(fc1_w, fc1_wT, 384, 1536);
    transpose_cast_kernel<<<(1536 * 384 + 255) / 256, 256, 0, stream>>>(fc2_w, fc2_wT, 1536, 384);

    // LN1 + shift + window partition -> bf16 win
    ln1_shift_window<<<M / 4, 256, 0, stream>>>(x, g1, b1, bufA);

    // qkv = win @ qkv_w + b  -> bf16
    gemm_kernel<0><<<dim3(M / 128, 1152 / 64), 256, 0, stream>>>(
        bufA, qkv_wT, qkv_b, bufBC, nullptr, M, 1152, 384);

    // windowed attention -> bufA (bf16)
    attn_kernel<<<dim3(1024, 12), 256, 0, stream>>>(bufBC, rpb, rel_idx, attn_mask, bufA);

    // proj + window reverse + unshift + residual x -> xmid (fp32)
    gemm_kernel<2><<<dim3(M / 128, 384 / 64), 256, 0, stream>>>(
        bufA, proj_wT, proj_b, xmid, x, M, 384, 384);

    // LN2 -> bufA (bf16)
    ln2_kernel<<<M / 4, 256, 0, stream>>>(xmid, g2, b2, bufA);

    // fc1 + GELU -> bufBC (bf16 h1)
    gemm_kernel<1><<<dim3(M / 128, 1536 / 64), 256, 0, stream>>>(
        bufA, fc1_wT, fc1_b, bufBC, nullptr, M, 1536, 384);

    // fc2 + residual xmid -> d_out (fp32)
    gemm_kernel<3><<<dim3(M / 128, 384 / 64), 256, 0, stream>>>(
        bufBC, fc2_wT, fc2_b, d_out, xmid, M, 384, 1536);
}

// Round 3
// 982.447 us; speedup vs baseline: 1.0295x; 1.0295x over previous
//
#include <hip/hip_runtime.h>
#include <hip/hip_bf16.h>
#include <math.h>

typedef __hip_bfloat16 bf16;
typedef __attribute__((ext_vector_type(8))) short short8;
typedef __attribute__((ext_vector_type(4))) float f32x4;

#define C_DIM 384
#define SS 3
#define SCALE_ATTN 0.17677669529663687f  // 32^-0.5
#define LN_EPS 1e-5f

typedef const __attribute__((address_space(1))) void g_cvoid;
typedef __attribute__((address_space(3))) void l_void;
__device__ __forceinline__ void gl_lds16(const void* g, void* l) {
    __builtin_amdgcn_global_load_lds((g_cvoid*)g, (l_void*)l, 16, 0, 0);
}

// ---------------------------------------------------------------------------
// Weight transpose + fp32->bf16 cast: in fp32 [R][Cc] -> out bf16 [Cc][R]
// ---------------------------------------------------------------------------
__global__ void transpose_cast_kernel(const float* __restrict__ in, bf16* __restrict__ out,
                                      int R, int Cc) {
    int idx = blockIdx.x * 256 + threadIdx.x;
    if (idx < R * Cc) {
        int r = idx / Cc, c = idx - r * Cc;
        out[(size_t)c * R + r] = __float2bfloat16(in[idx]);
    }
}

// ---------------------------------------------------------------------------
// LN1 + cyclic shift + window partition.  One wave per output token.
// ---------------------------------------------------------------------------
__global__ __launch_bounds__(256)
void ln1_shift_window(const float* __restrict__ x, const float* __restrict__ g,
                      const float* __restrict__ bta, bf16* __restrict__ win) {
    int wave = threadIdx.x >> 6, lane = threadIdx.x & 63;
    int token = blockIdx.x * 4 + wave;
    int bw = token / 49, ntk = token - bw * 49;
    int bb = bw >> 6, wi = bw & 63;
    int wh = wi >> 3, wwi = wi & 7;
    int rr = ntk / 7, cc = ntk - rr * 7;
    int hs = wh * 7 + rr + SS; if (hs >= 56) hs -= 56;
    int ws = wwi * 7 + cc + SS; if (ws >= 56) ws -= 56;
    const float* src = x + ((size_t)(bb * 3136 + hs * 56 + ws)) * C_DIM;

    float v[6]; float s = 0.f, sq = 0.f;
    #pragma unroll
    for (int j = 0; j < 6; j++) {
        v[j] = src[lane + j * 64];
        s += v[j]; sq += v[j] * v[j];
    }
    #pragma unroll
    for (int o = 32; o > 0; o >>= 1) { s += __shfl_xor(s, o, 64); sq += __shfl_xor(sq, o, 64); }
    float mean = s * (1.0f / 384.0f);
    float var  = sq * (1.0f / 384.0f) - mean * mean;
    float rstd = rsqrtf(var + LN_EPS);

    bf16* dst = win + (size_t)token * C_DIM;
    #pragma unroll
    for (int j = 0; j < 6; j++) {
        int c = lane + j * 64;
        dst[c] = __float2bfloat16((v[j] - mean) * rstd * g[c] + bta[c]);
    }
}

// ---------------------------------------------------------------------------
// LN2 over fp32 xmid -> bf16
// ---------------------------------------------------------------------------
__global__ __launch_bounds__(256)
void ln2_kernel(const float* __restrict__ xmid, const float* __restrict__ g,
                const float* __restrict__ bta, bf16* __restrict__ out) {
    int wave = threadIdx.x >> 6, lane = threadIdx.x & 63;
    int token = blockIdx.x * 4 + wave;
    const float* src = xmid + (size_t)token * C_DIM;
    float v[6]; float s = 0.f, sq = 0.f;
    #pragma unroll
    for (int j = 0; j < 6; j++) {
        v[j] = src[lane + j * 64];
        s += v[j]; sq += v[j] * v[j];
    }
    #pragma unroll
    for (int o = 32; o > 0; o >>= 1) { s += __shfl_xor(s, o, 64); sq += __shfl_xor(sq, o, 64); }
    float mean = s * (1.0f / 384.0f);
    float var  = sq * (1.0f / 384.0f) - mean * mean;
    float rstd = rsqrtf(var + LN_EPS);
    bf16* dst = out + (size_t)token * C_DIM;
    #pragma unroll
    for (int j = 0; j < 6; j++) {
        int c = lane + j * 64;
        dst[c] = __float2bfloat16((v[j] - mean) * rstd * g[c] + bta[c]);
    }
}

// ---------------------------------------------------------------------------
// MFMA bf16 GEMM (m97 structure): C[M,N] = A[M,K] @ W[K,N] (+ epilogue),
// W transposed (N,K) bf16.  BM=BN=128, BK=32, 4 waves in 2x2, each wave 64x64
// via 4x4 MFMA 16x16x32.  Staging: global_load_lds width=16, slot layout
// [panel(k/8)][row][8] (panel-major, lane-contiguous 16B slots).
// MODE 0: +bias -> bf16 out
// MODE 1: +bias, exact GELU -> bf16 out
// MODE 2: +bias, window-reverse + unshift scatter, + residual (fp32) -> fp32 out
// MODE 3: +bias, + residual fp32 -> fp32 out (d_out)
// ---------------------------------------------------------------------------
template <int MODE>
__global__ __launch_bounds__(256)
void gemm_kernel(const bf16* __restrict__ A, const bf16* __restrict__ BT,
                 const float* __restrict__ bias, void* __restrict__ out,
                 const float* __restrict__ resid, int M, int N, int K) {
    __shared__ bf16 As[4096];   // 4 panels * 128 rows * 8
    __shared__ bf16 Bs[4096];

    int tid = threadIdx.x;
    int wave = tid >> 6, lane = tid & 63, quad = lane >> 4, r = lane & 15;
    int wave_m = wave & 1, wave_n = wave >> 1;
    int m0 = blockIdx.x * 128, n0 = blockIdx.y * 128;

    f32x4 acc[4][4] = {};

    // per-wave staging slot indices (slot = panel*128 + row; 16B per slot)
    int sA0 = wave * 64 + lane;        // first A slot
    int sA1 = 256 + sA0;               // second A slot
    int pA0 = sA0 >> 7, rA0 = sA0 & 127;
    int pA1 = sA1 >> 7, rA1 = sA1 & 127;

    for (int k0 = 0; k0 < K; k0 += 32) {
        gl_lds16(A + (size_t)(m0 + rA0) * K + k0 + pA0 * 8, &As[(wave * 64) * 8]);
        gl_lds16(A + (size_t)(m0 + rA1) * K + k0 + pA1 * 8, &As[(256 + wave * 64) * 8]);
        gl_lds16(BT + (size_t)(n0 + rA0) * K + k0 + pA0 * 8, &Bs[(wave * 64) * 8]);
        gl_lds16(BT + (size_t)(n0 + rA1) * K + k0 + pA1 * 8, &Bs[(256 + wave * 64) * 8]);
        __syncthreads();

        short8 a[4], b[4];
        #pragma unroll
        for (int mt = 0; mt < 4; mt++)
            a[mt] = *(const short8*)&As[(quad * 128 + wave_m * 64 + mt * 16 + r) * 8];
        #pragma unroll
        for (int nt = 0; nt < 4; nt++)
            b[nt] = *(const short8*)&Bs[(quad * 128 + wave_n * 64 + nt * 16 + r) * 8];
        #pragma unroll
        for (int mt = 0; mt < 4; mt++)
            #pragma unroll
            for (int nt = 0; nt < 4; nt++)
                acc[mt][nt] = __builtin_amdgcn_mfma_f32_16x16x32_bf16(
                    a[mt], b[nt], acc[mt][nt], 0, 0, 0);
        __syncthreads();
    }

    // epilogue: m = m0 + wave_m*64 + mt*16 + quad*4 + reg ; n = n0 + wave_n*64 + nt*16 + r
    #pragma unroll
    for (int mt = 0; mt < 4; mt++) {
        #pragma unroll
        for (int nt = 0; nt < 4; nt++) {
            int n = n0 + wave_n * 64 + nt * 16 + r;
            float bv = bias[n];
            #pragma unroll
            for (int reg = 0; reg < 4; reg++) {
                int m = m0 + wave_m * 64 + mt * 16 + quad * 4 + reg;
                float v = acc[mt][nt][reg] + bv;
                if (MODE == 0) {
                    ((bf16*)out)[(size_t)m * N + n] = __float2bfloat16(v);
                } else if (MODE == 1) {
                    float gl = 0.5f * v * (1.0f + erff(v * 0.70710678118654752f));
                    ((bf16*)out)[(size_t)m * N + n] = __float2bfloat16(gl);
                } else if (MODE == 2) {
                    int bw = m / 49, ntk = m - bw * 49;
                    int bb = bw >> 6, wi = bw & 63;
                    int wh = wi >> 3, wwi = wi & 7;
                    int rr = ntk / 7, cc = ntk - rr * 7;
                    int ho = wh * 7 + rr + SS; if (ho >= 56) ho -= 56;
                    int wo = wwi * 7 + cc + SS; if (wo >= 56) wo -= 56;
                    size_t dst = ((size_t)(bb * 3136 + ho * 56 + wo)) * C_DIM + n;
                    ((float*)out)[dst] = v + resid[dst];
                } else {
                    size_t idx = (size_t)m * N + n;
                    ((float*)out)[idx] = v + resid[idx];
                }
            }
        }
    }
}

// ---------------------------------------------------------------------------
// Windowed attention: one block per (window, head).  qkv bf16: [1024*49, 1152]
// out bf16: [1024*49, 384].  Padded LDS (conflict-free), wave-per-row softmax.
// ---------------------------------------------------------------------------
__global__ __launch_bounds__(256)
void attn_kernel(const bf16* __restrict__ qkv, const float* __restrict__ rpb,
                 const int* __restrict__ rel_idx, const float* __restrict__ mask,
                 bf16* __restrict__ out) {
    __shared__ float qs[49][33], ks[49][33], vs[49][33];
    __shared__ float S[49][52];
    int bw = blockIdx.x, h = blockIdx.y;
    int tid = threadIdx.x;
    int wave = tid >> 6, lane = tid & 63;

    size_t base = (size_t)bw * 49 * 1152 + h * 32;
    for (int i = tid; i < 49 * 32; i += 256) {
        int n = i >> 5, d = i & 31;
        size_t rowoff = base + (size_t)n * 1152 + d;
        qs[n][d] = __bfloat162float(qkv[rowoff]) * SCALE_ATTN;
        ks[n][d] = __bfloat162float(qkv[rowoff + 384]);
        vs[n][d] = __bfloat162float(qkv[rowoff + 768]);
    }
    __syncthreads();

    int wi = bw & 63;
    for (int idx = tid; idx < 49 * 49; idx += 256) {
        int i = idx / 49, j = idx - i * 49;
        float acc = 0.f;
        #pragma unroll
        for (int d = 0; d < 32; d++) acc += qs[i][d] * ks[j][d];
        acc += rpb[rel_idx[idx] * 12 + h];
        acc += mask[(size_t)wi * 2401 + idx];
        S[i][j] = acc;
    }
    __syncthreads();

    // wave-per-row softmax
    for (int rrow = wave; rrow < 49; rrow += 4) {
        float v = (lane < 49) ? S[rrow][lane] : -1e30f;
        float m = v;
        #pragma unroll
        for (int o = 32; o > 0; o >>= 1) m = fmaxf(m, __shfl_xor(m, o, 64));
        float e = (lane < 49) ? __expf(v - m) : 0.f;
        float s = e;
        #pragma unroll
        for (int o = 32; o > 0; o >>= 1) s += __shfl_xor(s, o, 64);
        if (lane < 49) S[rrow][lane] = e / s;
    }
    __syncthreads();

    for (int i2 = tid; i2 < 49 * 32; i2 += 256) {
        int i = i2 >> 5, d = i2 & 31;
        float acc = 0.f;
        #pragma unroll
        for (int j = 0; j < 49; j++) acc += S[i][j] * vs[j][d];
        out[((size_t)bw * 49 + i) * 384 + h * 32 + d] = __float2bfloat16(acc);
    }
}

// ---------------------------------------------------------------------------
extern "C" void kernel_launch(void* const* d_in, const int* in_sizes, int n_in,
                              void* d_out, int out_size, void* d_ws, size_t ws_size,
                              hipStream_t stream) {
    const float* x      = (const float*)d_in[0];
    const float* g1     = (const float*)d_in[1];
    const float* b1     = (const float*)d_in[2];
    const float* qkv_w  = (const float*)d_in[3];
    const float* qkv_b  = (const float*)d_in[4];
    const float* rpb    = (const float*)d_in[5];
    const float* proj_w = (const float*)d_in[6];
    const float* proj_b = (const float*)d_in[7];
    const float* g2     = (const float*)d_in[8];
    const float* b2     = (const float*)d_in[9];
    const float* fc1_w  = (const float*)d_in[10];
    const float* fc1_b  = (const float*)d_in[11];
    const float* fc2_w  = (const float*)d_in[12];
    const float* fc2_b  = (const float*)d_in[13];
    const int*   rel_idx   = (const int*)d_in[14];
    const float* attn_mask = (const float*)d_in[15];

    const int M = 50176;  // 16 * 56 * 56 tokens = 1024 windows * 49

    char* ws = (char*)d_ws;
    size_t off = 0;
    bf16* bufA   = (bf16*)(ws + off); off += (size_t)M * 384 * 2;    // win / attn_out / ln2out
    bf16* bufBC  = (bf16*)(ws + off); off += (size_t)M * 1536 * 2;   // qkv (1152 cols) then h1 (1536)
    float* xmid  = (float*)(ws + off); off += (size_t)M * 384 * 4;   // residual mid, fp32
    bf16* qkv_wT  = (bf16*)(ws + off); off += (size_t)1152 * 384 * 2;
    bf16* proj_wT = (bf16*)(ws + off); off += (size_t)384 * 384 * 2;
    bf16* fc1_wT  = (bf16*)(ws + off); off += (size_t)1536 * 384 * 2;
    bf16* fc2_wT  = (bf16*)(ws + off); off += (size_t)384 * 1536 * 2;

    transpose_cast_kernel<<<(384 * 1152 + 255) / 256, 256, 0, stream>>>(qkv_w, qkv_wT, 384, 1152);
    transpose_cast_kernel<<<(384 * 384 + 255) / 256, 256, 0, stream>>>(proj_w, proj_wT, 384, 384);
    transpose_cast_kernel<<<(384 * 1536 + 255) / 256, 256, 0, stream>>>(fc1_w, fc1_wT, 384, 1536);
    transpose_cast_kernel<<<(1536 * 384 + 255) / 256, 256, 0, stream>>>(fc2_w, fc2_wT, 1536, 384);

    // LN1 + shift + window partition -> bf16 win
    ln1_shift_window<<<M / 4, 256, 0, stream>>>(x, g1, b1, bufA);

    // qkv = win @ qkv_w + b  -> bf16
    gemm_kernel<0><<<dim3(M / 128, 1152 / 128), 256, 0, stream>>>(
        bufA, qkv_wT, qkv_b, bufBC, nullptr, M, 1152, 384);

    // windowed attention -> bufA (bf16)
    attn_kernel<<<dim3(1024, 12), 256, 0, stream>>>(bufBC, rpb, rel_idx, attn_mask, bufA);

    // proj + window reverse + unshift + residual x -> xmid (fp32)
    gemm_kernel<2><<<dim3(M / 128, 384 / 128), 256, 0, stream>>>(
        bufA, proj_wT, proj_b, xmid, x, M, 384, 384);

    // LN2 -> bufA (bf16)
    ln2_kernel<<<M / 4, 256, 0, stream>>>(xmid, g2, b2, bufA);

    // fc1 + GELU -> bufBC (bf16 h1)
    gemm_kernel<1><<<dim3(M / 128, 1536 / 128), 256, 0, stream>>>(
        bufA, fc1_wT, fc1_b, bufBC, nullptr, M, 1536, 384);

    // fc2 + residual xmid -> d_out (fp32)
    gemm_kernel<3><<<dim3(M / 128, 384 / 128), 256, 0, stream>>>(
        bufBC, fc2_wT, fc2_b, d_out, xmid, M, 384, 1536);
}

// Round 5
// 805.561 us; speedup vs baseline: 1.2556x; 1.2196x over previous
//
#include <hip/hip_runtime.h>
#include <hip/hip_bf16.h>
#include <math.h>

typedef __hip_bfloat16 bf16;
typedef __attribute__((ext_vector_type(8))) short short8;
typedef __attribute__((ext_vector_type(4))) float f32x4;

#define C_DIM 384
#define SS 3
#define SCALE_ATTN 0.17677669529663687f  // 32^-0.5
#define LN_EPS 1e-5f

typedef const __attribute__((address_space(1))) void g_cvoid;
typedef __attribute__((address_space(3))) void l_void;
__device__ __forceinline__ void gl_lds16(const void* g, void* l) {
    __builtin_amdgcn_global_load_lds((g_cvoid*)g, (l_void*)l, 16, 0, 0);
}

// ---------------------------------------------------------------------------
// Weight transpose + fp32->bf16 cast: in fp32 [R][Cc] -> out bf16 [Cc][R]
// ---------------------------------------------------------------------------
__global__ void transpose_cast_kernel(const float* __restrict__ in, bf16* __restrict__ out,
                                      int R, int Cc) {
    int idx = blockIdx.x * 256 + threadIdx.x;
    if (idx < R * Cc) {
        int r = idx / Cc, c = idx - r * Cc;
        out[(size_t)c * R + r] = __float2bfloat16(in[idx]);
    }
}

// ---------------------------------------------------------------------------
// Fused bias table: BM[wi][h][64][64] fp32, padded; cols>=49 (or rows>=49)
// get -1e30 so attention needs no separate masking.
// ---------------------------------------------------------------------------
__global__ void build_bm_kernel(const float* __restrict__ rpb, const int* __restrict__ rel_idx,
                                const float* __restrict__ mask, float* __restrict__ BM) {
    int idx = blockIdx.x * 256 + threadIdx.x;   // < 64*12*4096
    int col = idx & 63, row = (idx >> 6) & 63;
    int h = (idx >> 12) % 12, wi = idx / (12 * 4096);
    float v = -1e30f;
    if (row < 49 && col < 49)
        v = rpb[rel_idx[row * 49 + col] * 12 + h] + mask[(size_t)wi * 2401 + row * 49 + col];
    BM[idx] = v;
}

// ---------------------------------------------------------------------------
// LN1 + cyclic shift + window partition.  One wave per output token.
// ---------------------------------------------------------------------------
__global__ __launch_bounds__(256)
void ln1_shift_window(const float* __restrict__ x, const float* __restrict__ g,
                      const float* __restrict__ bta, bf16* __restrict__ win) {
    int wave = threadIdx.x >> 6, lane = threadIdx.x & 63;
    int token = blockIdx.x * 4 + wave;
    int bw = token / 49, ntk = token - bw * 49;
    int bb = bw >> 6, wi = bw & 63;
    int wh = wi >> 3, wwi = wi & 7;
    int rr = ntk / 7, cc = ntk - rr * 7;
    int hs = wh * 7 + rr + SS; if (hs >= 56) hs -= 56;
    int ws = wwi * 7 + cc + SS; if (ws >= 56) ws -= 56;
    const float* src = x + ((size_t)(bb * 3136 + hs * 56 + ws)) * C_DIM;

    float v[6]; float s = 0.f, sq = 0.f;
    #pragma unroll
    for (int j = 0; j < 6; j++) {
        v[j] = src[lane + j * 64];
        s += v[j]; sq += v[j] * v[j];
    }
    #pragma unroll
    for (int o = 32; o > 0; o >>= 1) { s += __shfl_xor(s, o, 64); sq += __shfl_xor(sq, o, 64); }
    float mean = s * (1.0f / 384.0f);
    float var  = sq * (1.0f / 384.0f) - mean * mean;
    float rstd = rsqrtf(var + LN_EPS);

    bf16* dst = win + (size_t)token * C_DIM;
    #pragma unroll
    for (int j = 0; j < 6; j++) {
        int c = lane + j * 64;
        dst[c] = __float2bfloat16((v[j] - mean) * rstd * g[c] + bta[c]);
    }
}

// ---------------------------------------------------------------------------
// LN2 over fp32 xmid -> bf16
// ---------------------------------------------------------------------------
__global__ __launch_bounds__(256)
void ln2_kernel(const float* __restrict__ xmid, const float* __restrict__ g,
                const float* __restrict__ bta, bf16* __restrict__ out) {
    int wave = threadIdx.x >> 6, lane = threadIdx.x & 63;
    int token = blockIdx.x * 4 + wave;
    const float* src = xmid + (size_t)token * C_DIM;
    float v[6]; float s = 0.f, sq = 0.f;
    #pragma unroll
    for (int j = 0; j < 6; j++) {
        v[j] = src[lane + j * 64];
        s += v[j]; sq += v[j] * v[j];
    }
    #pragma unroll
    for (int o = 32; o > 0; o >>= 1) { s += __shfl_xor(s, o, 64); sq += __shfl_xor(sq, o, 64); }
    float mean = s * (1.0f / 384.0f);
    float var  = sq * (1.0f / 384.0f) - mean * mean;
    float rstd = rsqrtf(var + LN_EPS);
    bf16* dst = out + (size_t)token * C_DIM;
    #pragma unroll
    for (int j = 0; j < 6; j++) {
        int c = lane + j * 64;
        dst[c] = __float2bfloat16((v[j] - mean) * rstd * g[c] + bta[c]);
    }
}

// ---------------------------------------------------------------------------
// MFMA bf16 GEMM: BM=BN=128, BK=64, 4 waves 2x2, wave tile 64x64 (4x4 MFMA).
// Staging via global_load_lds width=16; LDS layout [panel(k/8)][row][8].
// MODE 0: +bias -> bf16 ; 1: +bias+GELU -> bf16 ; 2: +bias+scatter+resid -> f32
// MODE 3: +bias+resid -> f32
// ---------------------------------------------------------------------------
template <int MODE>
__global__ __launch_bounds__(256)
void gemm_kernel(const bf16* __restrict__ A, const bf16* __restrict__ BT,
                 const float* __restrict__ bias, void* __restrict__ out,
                 const float* __restrict__ resid, int M, int N, int K) {
    __shared__ bf16 As[8192];   // 8 panels * 128 rows * 8 = 16KB
    __shared__ bf16 Bs[8192];

    int tid = threadIdx.x;
    int wave = tid >> 6, lane = tid & 63, quad = lane >> 4, r = lane & 15;
    int wave_m = wave & 1, wave_n = wave >> 1;
    int m0 = blockIdx.x * 128, n0 = blockIdx.y * 128;

    f32x4 acc[4][4] = {};

    for (int k0 = 0; k0 < K; k0 += 64) {
        #pragma unroll
        for (int c = 0; c < 4; c++) {
            int slot = c * 256 + wave * 64 + lane;
            int panel = slot >> 7, row = slot & 127;
            gl_lds16(A + (size_t)(m0 + row) * K + k0 + panel * 8, &As[(c * 256 + wave * 64) * 8]);
            gl_lds16(BT + (size_t)(n0 + row) * K + k0 + panel * 8, &Bs[(c * 256 + wave * 64) * 8]);
        }
        __syncthreads();

        #pragma unroll
        for (int ks = 0; ks < 2; ks++) {
            int pq = ks * 4 + quad;
            short8 a[4], b[4];
            #pragma unroll
            for (int mt = 0; mt < 4; mt++)
                a[mt] = *(const short8*)&As[(pq * 128 + wave_m * 64 + mt * 16 + r) * 8];
            #pragma unroll
            for (int nt = 0; nt < 4; nt++)
                b[nt] = *(const short8*)&Bs[(pq * 128 + wave_n * 64 + nt * 16 + r) * 8];
            #pragma unroll
            for (int mt = 0; mt < 4; mt++)
                #pragma unroll
                for (int nt = 0; nt < 4; nt++)
                    acc[mt][nt] = __builtin_amdgcn_mfma_f32_16x16x32_bf16(
                        a[mt], b[nt], acc[mt][nt], 0, 0, 0);
        }
        __syncthreads();
    }

    #pragma unroll
    for (int mt = 0; mt < 4; mt++) {
        #pragma unroll
        for (int nt = 0; nt < 4; nt++) {
            int n = n0 + wave_n * 64 + nt * 16 + r;
            float bv = bias[n];
            #pragma unroll
            for (int reg = 0; reg < 4; reg++) {
                int m = m0 + wave_m * 64 + mt * 16 + quad * 4 + reg;
                float v = acc[mt][nt][reg] + bv;
                if (MODE == 0) {
                    ((bf16*)out)[(size_t)m * N + n] = __float2bfloat16(v);
                } else if (MODE == 1) {
                    float gl = 0.5f * v * (1.0f + erff(v * 0.70710678118654752f));
                    ((bf16*)out)[(size_t)m * N + n] = __float2bfloat16(gl);
                } else if (MODE == 2) {
                    int bw = m / 49, ntk = m - bw * 49;
                    int bb = bw >> 6, wi = bw & 63;
                    int wh = wi >> 3, wwi = wi & 7;
                    int rr = ntk / 7, cc = ntk - rr * 7;
                    int ho = wh * 7 + rr + SS; if (ho >= 56) ho -= 56;
                    int wo = wwi * 7 + cc + SS; if (wo >= 56) wo -= 56;
                    size_t dst = ((size_t)(bb * 3136 + ho * 56 + wo)) * C_DIM + n;
                    ((float*)out)[dst] = v + resid[dst];
                } else {
                    size_t idx = (size_t)m * N + n;
                    ((float*)out)[idx] = v + resid[idx];
                }
            }
        }
    }
}

// ---------------------------------------------------------------------------
// MFMA windowed attention.  Wave-per-(window,head); grid (1024, 3), 4 waves.
// QK^T fragments direct from global; softmax in-register (C/D layout);
// P & V^T via XOR-swizzled wave-private LDS; PV via MFMA.  No barriers.
// Padded rows (>=49) clamp their source row to 0 — NEVER read OOB (the
// region past qkv holds the BM table whose bf16 reinterpretation is ~1e30,
// which overflowed S to inf/NaN in round 4).
// ---------------------------------------------------------------------------
__global__ __launch_bounds__(256)
void attn_mfma_kernel(const bf16* __restrict__ qkv, const float* __restrict__ BM,
                      bf16* __restrict__ out) {
    __shared__ bf16 P_lds[4][4096];   // [wave][64*64] swizzled
    __shared__ bf16 V_lds[4][2048];   // [wave][32*64] swizzled (V^T)
    int wave = threadIdx.x >> 6, lane = threadIdx.x & 63;
    int quad = lane >> 4, m16 = lane & 15;
    int bw = blockIdx.x;
    int h = blockIdx.y * 4 + wave;
    int wi = bw & 63;

    const bf16* base = qkv + (size_t)bw * 49 * 1152 + h * 32;

    // ---- stage V^T (d-major, swizzled); pad cols n>=49 with zeros ----
    bf16* Vt = V_lds[wave];
    #pragma unroll
    for (int it = 0; it < 16; it++) {
        int idx = it * 64 + lane;          // n*16 + dpair
        int n = idx >> 4, dp = idx & 15;
        int d0 = dp * 2;
        unsigned val = 0;
        if (n < 49)
            val = *(const unsigned*)(base + (size_t)n * 1152 + 768 + d0);
        bf16 v0 = ((const bf16*)&val)[0], v1 = ((const bf16*)&val)[1];
        int cb = (n & 56);                  // chunk<<3
        Vt[d0 * 64 + ((cb ^ ((d0 & 7) << 3)) | (n & 7))] = v0;
        int d1 = d0 + 1;
        Vt[d1 * 64 + ((cb ^ ((d1 & 7) << 3)) | (n & 7))] = v1;
    }

    // ---- QK^T: fragments direct from global (rows>=49 clamped to row 0) ----
    short8 qf[4], kf[4];
    #pragma unroll
    for (int t = 0; t < 4; t++) {
        int row = t * 16 + m16;
        int rc = (row < 49) ? row : 0;
        qf[t] = *(const short8*)(base + (size_t)rc * 1152 + quad * 8);
        kf[t] = *(const short8*)(base + (size_t)rc * 1152 + 384 + quad * 8);
    }
    f32x4 S[4][4] = {};
    #pragma unroll
    for (int mt = 0; mt < 4; mt++)
        #pragma unroll
        for (int nt = 0; nt < 4; nt++)
            S[mt][nt] = __builtin_amdgcn_mfma_f32_16x16x32_bf16(qf[mt], kf[nt], S[mt][nt], 0, 0, 0);

    // ---- scale + fused bias/mask + softmax (in C/D layout) ----
    const float* bmw = BM + (((size_t)wi * 12 + h) << 12);
    bf16* Pw = P_lds[wave];
    #pragma unroll
    for (int mt = 0; mt < 4; mt++) {
        #pragma unroll
        for (int reg = 0; reg < 4; reg++) {
            int row = mt * 16 + quad * 4 + reg;
            float p[4];
            float mx = -1e30f;
            #pragma unroll
            for (int nt = 0; nt < 4; nt++) {
                int col = nt * 16 + m16;
                float s = S[mt][nt][reg] * SCALE_ATTN + bmw[row * 64 + col];
                p[nt] = s;
                mx = fmaxf(mx, s);
            }
            #pragma unroll
            for (int o = 1; o < 16; o <<= 1) mx = fmaxf(mx, __shfl_xor(mx, o, 64));
            float sm = 0.f;
            #pragma unroll
            for (int nt = 0; nt < 4; nt++) { p[nt] = __expf(p[nt] - mx); sm += p[nt]; }
            #pragma unroll
            for (int o = 1; o < 16; o <<= 1) sm += __shfl_xor(sm, o, 64);
            float inv = 1.0f / sm;
            int r7 = (row & 7) << 3;
            #pragma unroll
            for (int nt = 0; nt < 4; nt++) {
                int col = nt * 16 + m16;
                int sw = ((col & 56) ^ r7) | (col & 7);
                Pw[row * 64 + sw] = __float2bfloat16(p[nt] * inv);
            }
        }
    }

    // ---- PV via MFMA (K=64 over padded n; pad cols of P are exactly 0) ----
    f32x4 O[4][2] = {};
    #pragma unroll
    for (int ks = 0; ks < 2; ks++) {
        int chunk = ks * 4 + quad;
        short8 pa[4], vb[2];
        #pragma unroll
        for (int mt = 0; mt < 4; mt++) {
            int row = mt * 16 + m16;
            pa[mt] = *(const short8*)&Pw[row * 64 + ((chunk ^ (row & 7)) << 3)];
        }
        #pragma unroll
        for (int nt = 0; nt < 2; nt++) {
            int d = nt * 16 + m16;
            vb[nt] = *(const short8*)&Vt[d * 64 + ((chunk ^ (d & 7)) << 3)];
        }
        #pragma unroll
        for (int mt = 0; mt < 4; mt++)
            #pragma unroll
            for (int nt = 0; nt < 2; nt++)
                O[mt][nt] = __builtin_amdgcn_mfma_f32_16x16x32_bf16(pa[mt], vb[nt], O[mt][nt], 0, 0, 0);
    }

    // ---- store [token][h*32+d], rows < 49 only ----
    bf16* orow = out + (size_t)bw * 49 * 384 + h * 32;
    #pragma unroll
    for (int mt = 0; mt < 4; mt++) {
        #pragma unroll
        for (int reg = 0; reg < 4; reg++) {
            int row = mt * 16 + quad * 4 + reg;
            if (row < 49) {
                #pragma unroll
                for (int nt = 0; nt < 2; nt++)
                    orow[(size_t)row * 384 + nt * 16 + m16] = __float2bfloat16(O[mt][nt][reg]);
            }
        }
    }
}

// ---------------------------------------------------------------------------
extern "C" void kernel_launch(void* const* d_in, const int* in_sizes, int n_in,
                              void* d_out, int out_size, void* d_ws, size_t ws_size,
                              hipStream_t stream) {
    const float* x      = (const float*)d_in[0];
    const float* g1     = (const float*)d_in[1];
    const float* b1     = (const float*)d_in[2];
    const float* qkv_w  = (const float*)d_in[3];
    const float* qkv_b  = (const float*)d_in[4];
    const float* rpb    = (const float*)d_in[5];
    const float* proj_w = (const float*)d_in[6];
    const float* proj_b = (const float*)d_in[7];
    const float* g2     = (const float*)d_in[8];
    const float* b2     = (const float*)d_in[9];
    const float* fc1_w  = (const float*)d_in[10];
    const float* fc1_b  = (const float*)d_in[11];
    const float* fc2_w  = (const float*)d_in[12];
    const float* fc2_b  = (const float*)d_in[13];
    const int*   rel_idx   = (const int*)d_in[14];
    const float* attn_mask = (const float*)d_in[15];

    const int M = 50176;  // 16 * 56 * 56 tokens = 1024 windows * 49

    char* ws = (char*)d_ws;
    size_t off = 0;
    bf16* bufA   = (bf16*)(ws + off); off += (size_t)M * 384 * 2;    // win / attn_out / ln2out
    bf16* bufBC  = (bf16*)(ws + off); off += (size_t)M * 1536 * 2;   // qkv (1152 cols) then h1 (1536)
    float* xmid  = (float*)(ws + off); off += (size_t)M * 384 * 4;   // residual mid, fp32
    bf16* qkv_wT  = (bf16*)(ws + off); off += (size_t)1152 * 384 * 2;
    bf16* proj_wT = (bf16*)(ws + off); off += (size_t)384 * 384 * 2;
    bf16* fc1_wT  = (bf16*)(ws + off); off += (size_t)1536 * 384 * 2;
    bf16* fc2_wT  = (bf16*)(ws + off); off += (size_t)384 * 1536 * 2;
    // BM table lives in the unused tail of bufBC (qkv uses only 1152 of 1536 cols)
    float* BM = (float*)(bufBC + (size_t)M * 1152);   // 64*12*64*64 f32 = 12.6MB < 38.5MB free

    build_bm_kernel<<<64 * 12 * 4096 / 256, 256, 0, stream>>>(rpb, rel_idx, attn_mask, BM);

    transpose_cast_kernel<<<(384 * 1152 + 255) / 256, 256, 0, stream>>>(qkv_w, qkv_wT, 384, 1152);
    transpose_cast_kernel<<<(384 * 384 + 255) / 256, 256, 0, stream>>>(proj_w, proj_wT, 384, 384);
    transpose_cast_kernel<<<(384 * 1536 + 255) / 256, 256, 0, stream>>>(fc1_w, fc1_wT, 384, 1536);
    transpose_cast_kernel<<<(1536 * 384 + 255) / 256, 256, 0, stream>>>(fc2_w, fc2_wT, 1536, 384);

    // LN1 + shift + window partition -> bf16 win
    ln1_shift_window<<<M / 4, 256, 0, stream>>>(x, g1, b1, bufA);

    // qkv = win @ qkv_w + b  -> bf16
    gemm_kernel<0><<<dim3(M / 128, 1152 / 128), 256, 0, stream>>>(
        bufA, qkv_wT, qkv_b, bufBC, nullptr, M, 1152, 384);

    // windowed attention (MFMA) -> bufA (bf16)
    attn_mfma_kernel<<<dim3(1024, 3), 256, 0, stream>>>(bufBC, BM, bufA);

    // proj + window reverse + unshift + residual x -> xmid (fp32)
    gemm_kernel<2><<<dim3(M / 128, 384 / 128), 256, 0, stream>>>(
        bufA, proj_wT, proj_b, xmid, x, M, 384, 384);

    // LN2 -> bufA (bf16)
    ln2_kernel<<<M / 4, 256, 0, stream>>>(xmid, g2, b2, bufA);

    // fc1 + GELU -> bufBC (bf16 h1)
    gemm_kernel<1><<<dim3(M / 128, 1536 / 128), 256, 0, stream>>>(
        bufA, fc1_wT, fc1_b, bufBC, nullptr, M, 1536, 384);

    // fc2 + residual xmid -> d_out (fp32)
    gemm_kernel<3><<<dim3(M / 128, 384 / 128), 256, 0, stream>>>(
        bufBC, fc2_wT, fc2_b, d_out, xmid, M, 384, 1536);
}